// Round 3
// baseline (11845.968 us; speedup 1.0000x reference)
//
#include <hip/hip_runtime.h>
#include <stdint.h>

// LSTM(relu) persistent kernel v3: B=64,S=1024,F=128,H=512.
// 256 wgs x 64 threads = 256 independent waves, 1 per CU.
// Wave (grp, wid): computes 8 units (u0=wid*8) for 16 batch rows (grp*16..+15).
// U and W live entirely in VGPRs as operand-swapped MFMA A-frags (z^T = [U;W]^T [h;x]^T);
// launch_bounds(64,1) -> ~512 VGPR budget, no spill (v2's 128-cap spill was the regression).
// No LDS, no __syncthreads. h exchange: double-buffered global bf16 + per-WAVE
// release flag; consumers poll all 64 producer flags with one lane-parallel load.

#define B_ 64
#define S_ 1024
#define F_ 128
#define H_ 512
#define G4_ 2048
#define GROUPS 4
#define BG_ 16          // batch rows per group
#define WPG 64          // waves per group
#define UW 8            // units per wave
#define TILES 2         // 4 units per D-tile (16 zcols = 4 gates x 4 units)
#define KH 16           // h@U K-steps (512/32)
#define KX 4            // x@W K-steps (128/32)
#define KT 20
#define HBUF_ELEMS (B_ * H_)

typedef __attribute__((ext_vector_type(8))) short short8;  // 8 x bf16
typedef __attribute__((ext_vector_type(4))) float f32x4;

__device__ __forceinline__ unsigned short f2bf(float f) {
  union { float f; unsigned u; } v; v.f = f;
  unsigned u = v.u + 0x7fffu + ((v.u >> 16) & 1u);   // RNE
  return (unsigned short)(u >> 16);
}

__device__ __forceinline__ short8 pack2(f32x4 a, f32x4 b) {
  short8 r;
#pragma unroll
  for (int i = 0; i < 4; ++i) r[i] = (short)f2bf(a[i]);
#pragma unroll
  for (int i = 0; i < 4; ++i) r[4 + i] = (short)f2bf(b[i]);
  return r;
}

__global__ __launch_bounds__(64, 1) void lstm_pers(
    const float* __restrict__ x, const float* __restrict__ W,
    const float* __restrict__ U, const float* __restrict__ bias,
    float* __restrict__ out, unsigned int* flags, unsigned short* hbuf) {

  const int lane = threadIdx.x;        // one wave per wg
  const int l15  = lane & 15;
  const int l4   = lane >> 4;          // 0..3
  const int koff = l4 * 8;

  const int blk   = blockIdx.x;        // 0..255
  const int grp   = blk & 3;           // batch group (keeps a group on ~2 XCDs)
  const int wid   = blk >> 2;          // 0..63: wave-in-group
  const int u0    = wid * UW;
  const int bbase = grp * BG_;

  unsigned int* gflags = flags + (size_t)grp * WPG * 16;  // 64B-spaced flags
  unsigned int* myflag = gflags + wid * 16;
  unsigned int* pollp  = gflags + lane * 16;              // lane polls wave 'lane'

  // ---- one-time: [U;W]^T A-fragments into registers ----
  // A[m = l15][k = koff+jj] = M[k][zcol(m)], zcol(m) = (m&3)*H + u0 + tl*4 + (m>>2)
  const int gate_a = l15 & 3;
  const int usub_a = l15 >> 2;
  short8 au[TILES][KT];
#pragma unroll
  for (int tl = 0; tl < TILES; ++tl) {
    const int zcol = gate_a * H_ + u0 + tl * 4 + usub_a;
#pragma unroll
    for (int ks = 0; ks < KT; ++ks) {
      short8 v;
#pragma unroll
      for (int jj = 0; jj < 8; ++jj) {
        const int k = ks * 32 + koff + jj;
        const float f = (ks < KH) ? U[(size_t)k * G4_ + zcol]
                                  : W[(size_t)(k - H_) * G4_ + zcol];
        v[jj] = (short)f2bf(f);
      }
      au[tl][ks] = v;
    }
  }

  // D-side mapping: reg r = gate r, unit = u0 + tl*4 + l4, batch row = bbase + l15
  float bias_r[TILES][4];
#pragma unroll
  for (int tl = 0; tl < TILES; ++tl)
#pragma unroll
    for (int g = 0; g < 4; ++g)
      bias_r[tl][g] = bias[g * H_ + u0 + tl * 4 + l4];

  float cst[TILES] = {0.f, 0.f};

  const float* xrow = x + ((size_t)(bbase + l15) * S_) * F_ + koff;
  const unsigned short* hrow0 = hbuf + (size_t)(bbase + l15) * H_ + koff;
  const int brow = bbase + l15;

  auto load_x = [&](int t, short8 (&bx)[KX]) {
    const float* xt = xrow + (size_t)t * F_;
#pragma unroll
    for (int q = 0; q < KX; ++q) {
      f32x4 a = *(const f32x4*)(xt + q * 32);
      f32x4 b = *(const f32x4*)(xt + q * 32 + 4);
      bx[q] = pack2(a, b);
    }
  };

  auto step = [&](int t, short8 (&bx_c)[KX], short8 (&bx_n)[KX]) {
    // ---- wait for h(t-1) from all 64 waves of this group ----
    if (t > 0) {
      const unsigned tgt = (unsigned)t;
      while (true) {
        unsigned v = __hip_atomic_load(pollp, __ATOMIC_RELAXED, __HIP_MEMORY_SCOPE_AGENT);
        if (__all((int)(v >= tgt))) break;
      }
      (void)__hip_atomic_load(myflag, __ATOMIC_ACQUIRE, __HIP_MEMORY_SCOPE_AGENT);
    }

    // ---- issue all h B-frag loads immediately (latency hidden by x@W MFMAs) ----
    short8 bh[KH];
    if (t > 0) {
      const unsigned short* hr = hrow0 + (size_t)(t & 1) * HBUF_ELEMS;
#pragma unroll
      for (int ks = 0; ks < KH; ++ks)
        bh[ks] = *(const short8*)(hr + ks * 32);
    }

    // ---- acc = bias; x @ W while h loads are in flight ----
    f32x4 acc[TILES];
#pragma unroll
    for (int tl = 0; tl < TILES; ++tl) {
      f32x4 a; a[0] = bias_r[tl][0]; a[1] = bias_r[tl][1];
      a[2] = bias_r[tl][2]; a[3] = bias_r[tl][3];
      acc[tl] = a;
    }
#pragma unroll
    for (int q = 0; q < KX; ++q)
#pragma unroll
      for (int tl = 0; tl < TILES; ++tl)
        acc[tl] = __builtin_amdgcn_mfma_f32_16x16x32_bf16(au[tl][KH + q], bx_c[q], acc[tl], 0, 0, 0);

    // ---- prefetch + pack x for step t+1 (independent of h) ----
    load_x((t + 1) & (S_ - 1), bx_n);

    // ---- h(t-1) @ U ----
    if (t > 0) {
#pragma unroll
      for (int ks = 0; ks < KH; ++ks)
#pragma unroll
        for (int tl = 0; tl < TILES; ++tl)
          acc[tl] = __builtin_amdgcn_mfma_f32_16x16x32_bf16(au[tl][ks], bh[ks], acc[tl], 0, 0, 0);
    }

    // ---- gates: regs 0..3 of each tile = i,f,g,o of one (row,unit) ----
    unsigned short* hw = hbuf + (size_t)((t + 1) & 1) * HBUF_ELEMS;
#pragma unroll
    for (int tl = 0; tl < TILES; ++tl) {
      const float zi = acc[tl][0], zf = acc[tl][1], zg = acc[tl][2], zo = acc[tl][3];
      const float ig = 1.f / (1.f + __expf(-zi));
      const float fg = 1.f / (1.f + __expf(-zf));
      const float gg = fmaxf(zg, 0.f);              // relu candidate
      const float og = 1.f / (1.f + __expf(-zo));
      const float cn = fg * cst[tl] + ig * gg;
      cst[tl] = cn;
      const float h = og * fmaxf(cn, 0.f);          // relu output activation
      const int unit = u0 + tl * 4 + l4;
      hw[(size_t)brow * H_ + unit] = f2bf(h);
      __builtin_nontemporal_store(h, &out[((size_t)brow * S_ + t) * H_ + unit]);
    }

    // ---- publish this wave's h slice ----
    if (lane == 0)
      __hip_atomic_store(myflag, (unsigned)(t + 1), __ATOMIC_RELEASE, __HIP_MEMORY_SCOPE_AGENT);
  };

  short8 bxA[KX], bxB[KX];
  load_x(0, bxA);
  for (int t = 0; t < S_; t += 2) {
    step(t, bxA, bxB);
    step(t + 1, bxB, bxA);
  }
}

extern "C" void kernel_launch(void* const* d_in, const int* in_sizes, int n_in,
                              void* d_out, int out_size, void* d_ws, size_t ws_size,
                              hipStream_t stream) {
  const float* x = (const float*)d_in[0];
  const float* W = (const float*)d_in[1];
  const float* U = (const float*)d_in[2];
  const float* b = (const float*)d_in[3];
  float* out = (float*)d_out;

  unsigned int*   flags = (unsigned int*)d_ws;                     // 4*64 flags, 64B apart = 16KB
  unsigned short* hbuf  = (unsigned short*)((char*)d_ws + 16384);  // 2 x 64 x 512 bf16 = 128KB

  hipMemsetAsync(d_ws, 0, 16384, stream);   // zero flags each launch/replay

  lstm_pers<<<dim3(GROUPS * WPG), dim3(64), 0, stream>>>(x, W, U, b, out, flags, hbuf);
}